// Round 18
// baseline (552.055 us; speedup 1.0000x reference)
//
#include <hip/hip_runtime.h>
#include <math.h>

#define SB 64          // samples per block (16 per wave, 4 waves)
#define NTHREADS 256

typedef short short8 __attribute__((ext_vector_type(8)));
typedef float f32x4  __attribute__((ext_vector_type(4)));

__device__ __forceinline__ unsigned short f2bf(float f) {
    unsigned int u = __builtin_bit_cast(unsigned int, f);
    unsigned int r = (u + 0x7FFFu + ((u >> 16) & 1u)) >> 16;   // RNE
    return (unsigned short)r;
}
__device__ __forceinline__ float bf2f(unsigned short h) {
    unsigned int u = ((unsigned int)h) << 16;
    return __builtin_bit_cast(float, u);
}
__device__ __forceinline__ unsigned pack2(unsigned short lo, unsigned short hi) {
    return (unsigned)lo | ((unsigned)hi << 16);
}
__device__ __forceinline__ float softplus_f(float z) {
    return z > 15.f ? z : log1pf(expf(z));
}
__device__ __forceinline__ float fast_tanh(float z) {
    const float e = __builtin_amdgcn_exp2f(z * 2.8853900817779268f);
    return fmaf(-2.f, __builtin_amdgcn_rcpf(e + 1.f), 1.f);
}
__device__ __forceinline__ unsigned selv(bool c, unsigned a, unsigned b) {
    return c ? a : b;
}
__device__ __forceinline__ unsigned sx(unsigned v, int m) {
    return (unsigned)__shfl_xor((int)v, m);
}

// ---------------- prep: pack W1 (split hi/lo) + W0 + head weights ----------------
// wB (short8 slots): nt*1024 + [hi: ks*64+l | lo: 512+ks*64+l]
// slot element i: B[k][n], k = ks*32 + (l>>4)*8 + i, n = nt*16 + (l&15)
__global__ void prep(const float* __restrict__ W1, const float* __restrict__ W0,
                     const float* __restrict__ Wd, const float* __restrict__ Wo,
                     const float* __restrict__ Wv,
                     unsigned short* __restrict__ wB,
                     float4* __restrict__ w0p, float4* __restrict__ hwp)
{
    int idx = blockIdx.x * blockDim.x + threadIdx.x;
    if (idx < 256) {
        w0p[idx] = make_float4(W0[idx], W0[256 + idx], W0[512 + idx], W0[768 + idx]);
        hwp[idx] = make_float4(Wd[2 * idx], Wd[2 * idx + 1], Wo[idx], Wv[idx]);
    }
    if (idx < 8192) {
        const int l  = idx & 63;
        const int ks = (idx >> 6) & 7;
        const int nt = idx >> 9;
        const int k0 = ks * 32 + (l >> 4) * 8;
        const int n  = nt * 16 + (l & 15);
        const int hbase = (nt * 1024 + ks * 64 + l) * 8;
        const int lbase = (nt * 1024 + 512 + ks * 64 + l) * 8;
        #pragma unroll
        for (int i = 0; i < 8; ++i) {
            const float f = W1[(k0 + i) * 256 + n];
            const unsigned short hi = f2bf(f);
            const unsigned short lo = f2bf(f - bf2f(hi));
            wB[hbase + i] = hi;
            wB[lbase + i] = lo;
        }
    }
}

// Build one 16-row A fragment set (rows = rho*4+s: h_hi,h_lo,ta,tb x 4 samples).
// Identical arithmetic + exchange (xor 4/8/12) to the r9/r11-passing kernels.
__device__ __forceinline__ void build_aF(
    const float4* __restrict__ w0p, const float* __restrict__ b0,
    int kg, int rho, bool rb0, bool rb1,
    float sn0, float cs0, float sn1, float cs1, short8* aF)
{
    #pragma unroll
    for (int ks = 0; ks < 8; ++ks) {
        const int j0 = ks * 32 + kg * 8 + 2 * rho;
        const float4 wa = w0p[j0];
        const float4 wb = w0p[j0 + 1];
        const float2 bb = *reinterpret_cast<const float2*>(&b0[j0]);
        float z0 = bb.x;
        z0 = fmaf(cs0, wa.x, z0); z0 = fmaf(cs1, wa.y, z0);
        z0 = fmaf(sn0, wa.z, z0); z0 = fmaf(sn1, wa.w, z0);
        float z1 = bb.y;
        z1 = fmaf(cs0, wb.x, z1); z1 = fmaf(cs1, wb.y, z1);
        z1 = fmaf(sn0, wb.z, z1); z1 = fmaf(sn1, wb.w, z1);
        const float h0 = fast_tanh(z0);
        const float h1 = fast_tanh(z1);
        const unsigned short h0h = f2bf(h0);
        const unsigned short h1h = f2bf(h1);
        const unsigned short h0l = f2bf(h0 - bf2f(h0h));
        const unsigned short h1l = f2bf(h1 - bf2f(h1h));
        const float dt0 = fmaf(-h0, h0, 1.f);
        const float dt1 = fmaf(-h1, h1, 1.f);
        const float ta0 = dt0 * fmaf(-sn0, wa.x, cs0 * wa.z);
        const float ta1 = dt1 * fmaf(-sn0, wb.x, cs0 * wb.z);
        const float tb0 = dt0 * fmaf(-sn1, wa.y, cs1 * wa.w);
        const float tb1 = dt1 * fmaf(-sn1, wb.y, cs1 * wb.w);
        const unsigned v0 = pack2(h0h, h1h);
        const unsigned v1 = pack2(h0l, h1l);
        const unsigned v2 = pack2(f2bf(ta0), f2bf(ta1));
        const unsigned v3 = pack2(f2bf(tb0), f2bf(tb1));
        const unsigned s0 = selv(rb1, selv(rb0, v3, v2), selv(rb0, v1, v0));
        const unsigned s1 = selv(rb1, selv(rb0, v2, v3), selv(rb0, v0, v1));
        const unsigned s2 = selv(rb1, selv(rb0, v1, v0), selv(rb0, v3, v2));
        const unsigned s3 = selv(rb1, selv(rb0, v0, v1), selv(rb0, v2, v3));
        const unsigned r4  = sx(s1, 4);
        const unsigned r8  = sx(s2, 8);
        const unsigned r12 = sx(s3, 12);
        const unsigned w0 = selv(rb1, selv(rb0, r12, r8), selv(rb0, r4, s0));
        const unsigned w1 = selv(rb1, selv(rb0, r8, r12), selv(rb0, s0, r4));
        const unsigned w2 = selv(rb1, selv(rb0, r4, s0), selv(rb0, r12, r8));
        const unsigned w3 = selv(rb1, selv(rb0, s0, r4), selv(rb0, r8, r12));
        aF[ks] = __builtin_bit_cast(short8, make_uint4(w0, w1, w2, w3));
    }
}

// quadrant-dedup'd epilogue accumulation, single merged-C variant.
__device__ __forceinline__ void epi_acc(
    const f32x4& cs, float b1v, const float4& hw,
    bool qb0, bool qb1, bool qlt2,
    float* u0, float* u1, float* u2, float* u3)
{
    float zs[4], zf[4], zA[4];
    #pragma unroll
    for (int r = 0; r < 4; ++r) zs[r] = cs[r];
    #pragma unroll
    for (int r = 0; r < 4; ++r) zf[r] = zs[r] + __shfl_xor(zs[r], 16) + b1v;
    #pragma unroll
    for (int r = 0; r < 4; ++r) {
        const float zr = __shfl_xor(zf[r], 32);
        zA[r] = qlt2 ? zf[r] : zr;
    }
    const float zpick = qb1 ? (qb0 ? zA[3] : zA[2]) : (qb0 ? zA[1] : zA[0]);
    const float hq = fast_tanh(zpick);
    const float g1 = __shfl_xor(hq, 16);
    const float g2 = __shfl_xor(hq, 32);
    const float g3 = __shfl_xor(hq, 48);
    float hr[4];
    hr[0] = qb1 ? (qb0 ? g3 : g2) : (qb0 ? g1 : hq);
    hr[1] = qb1 ? (qb0 ? g2 : g3) : (qb0 ? hq : g1);
    hr[2] = qb1 ? (qb0 ? g1 : hq) : (qb0 ? g3 : g2);
    hr[3] = qb1 ? (qb0 ? hq : g1) : (qb0 ? g2 : g3);
    #pragma unroll
    for (int r = 0; r < 4; ++r) {
        const float dt  = fmaf(-hr[r], hr[r], 1.f);
        const float val = qlt2 ? hr[r] : dt * zs[r];
        u0[r] = fmaf(val, hw.x, u0[r]);
        u1[r] = fmaf(val, hw.y, u1[r]);
        u2[r] = fmaf(val, hw.z, u2[r]);
        u3[r] = fmaf(val, hw.w, u3[r]);
    }
}

// scalar per-sample dynamics solve + output write (r11 body, unchanged)
__device__ __forceinline__ void solve_write(
    const float* __restrict__ x, float* __restrict__ out, int sg,
    float phd0, float phd1, float phoo,
    float pad0, float pad1, float pao, float pav,
    float pbd0, float pbd1, float pbo, float pbv,
    float bd0, float bd1, float bo0)
{
    const float u    = x[sg * 6 + 2];
    const float vv   = x[sg * 6 + 3];
    const float tau0 = x[sg * 6 + 4];
    const float tau1 = x[sg * 6 + 5];

    const float zd0 = phd0 + bd0;
    const float zd1 = phd1 + bd1;
    const float zo  = phoo + bo0;

    const float ld0 = softplus_f(zd0) + 1e-4f;
    const float ld1 = softplus_f(zd1) + 1e-4f;
    const float lo  = zo;

    const float sg0 = 1.f / (1.f + expf(-zd0));
    const float sg1 = 1.f / (1.f + expf(-zd1));

    const float ld0a = sg0 * pad0, ld0b = sg0 * pbd0;
    const float ld1a = sg1 * pad1, ld1b = sg1 * pbd1;
    const float loa  = pao,        lob  = pbo;
    const float ga   = pav,        gb   = pbv;

    const float H00 = fmaf(ld0, ld0, 1e-4f);
    const float H01 = ld0 * lo;
    const float H11 = fmaf(lo, lo, fmaf(ld1, ld1, 1e-4f));

    const float dH00a = 2.f * ld0 * ld0a, dH00b = 2.f * ld0 * ld0b;
    const float dH01a = fmaf(ld0a, lo, ld0 * loa);
    const float dH01b = fmaf(ld0b, lo, ld0 * lob);
    const float dH11a = 2.f * fmaf(lo, loa, ld1 * ld1a);
    const float dH11b = 2.f * fmaf(lo, lob, ld1 * ld1b);

    const float wa0 = fmaf(dH00a, u, dH01a * vv);
    const float wa1 = fmaf(dH01a, u, dH11a * vv);
    const float wb0 = fmaf(dH00b, u, dH01b * vv);
    const float wb1 = fmaf(dH01b, u, dH11b * vv);

    const float QFa = dH00a*u*u + 2.f*dH01a*u*vv + dH11a*vv*vv;
    const float QFb = dH00b*u*u + 2.f*dH01b*u*vv + dH11b*vv*vv;

    const float C0 = fmaf(wa0, u, wb0 * vv) - 0.5f * QFa;
    const float C1 = fmaf(wa1, u, wb1 * vv) - 0.5f * QFb;

    const float r0 = tau0 - C0 - ga;
    const float r1 = tau1 - C1 - gb;

    const float det = fmaf(H00, H11, -H01 * H01);
    const float inv = 1.f / det;
    const float qdd0 = (H11 * r0 - H01 * r1) * inv;
    const float qdd1 = (H00 * r1 - H01 * r0) * inv;

    float2* o = reinterpret_cast<float2*>(&out[sg * 6]);
    o[0] = make_float2(u, vv);
    o[1] = make_float2(qdd0, qdd1);
    o[2] = make_float2(0.f, 0.f);
}

// r17 barrier-free skeleton, 4 A-sets (16 samples/wave): halves L2 B-stream
// per sample. No LDS, no __syncthreads — pure register dataflow.
__global__ __launch_bounds__(NTHREADS, 1)
void lode_mfma(const float* __restrict__ x,
               const float4* __restrict__ w0p, const float* __restrict__ b0,
               const unsigned short* __restrict__ wB,
               const float* __restrict__ b1,
               const float4* __restrict__ hwp,
               const float* __restrict__ bd, const float* __restrict__ bo,
               float* __restrict__ out, int n)
{
    const int tid  = threadIdx.x;
    const int wave = tid >> 6;
    const int lane = tid & 63;
    const int r15  = lane & 15;
    const int s    = r15 & 3;
    const int rho  = r15 >> 2;
    const bool rb0 = (rho & 1) != 0;
    const bool rb1 = (rho & 2) != 0;
    const int kg   = lane >> 4;

    // ---------------- phase 1: four A-fragment sets (samples base + s + 4k) ----
    const int sbase = blockIdx.x * SB + wave * 16 + s;
    int sgA = sbase;
    int sgB = sbase + 4;
    int sgC = sbase + 8;
    int sgD = sbase + 12;
    if (sgA >= n) sgA = n - 1;
    if (sgB >= n) sgB = n - 1;
    if (sgC >= n) sgC = n - 1;
    if (sgD >= n) sgD = n - 1;

    short8 aFA[8], aFB[8], aFC[8], aFD[8];
    {
        const float qA0 = x[sgA * 6 + 0], qA1 = x[sgA * 6 + 1];
        float ss_, cc_;
        sincosf(rb0 ? qA1 : qA0, &ss_, &cc_);
        const float sso = __shfl_xor(ss_, 4), cco = __shfl_xor(cc_, 4);
        const float sn0 = rb0 ? sso : ss_, cs0 = rb0 ? cco : cc_;
        const float sn1 = rb0 ? ss_ : sso, cs1 = rb0 ? cc_ : cco;
        build_aF(w0p, b0, kg, rho, rb0, rb1, sn0, cs0, sn1, cs1, aFA);
    }
    {
        const float qB0 = x[sgB * 6 + 0], qB1 = x[sgB * 6 + 1];
        float ss_, cc_;
        sincosf(rb0 ? qB1 : qB0, &ss_, &cc_);
        const float sso = __shfl_xor(ss_, 4), cco = __shfl_xor(cc_, 4);
        const float sn0 = rb0 ? sso : ss_, cs0 = rb0 ? cco : cc_;
        const float sn1 = rb0 ? ss_ : sso, cs1 = rb0 ? cc_ : cco;
        build_aF(w0p, b0, kg, rho, rb0, rb1, sn0, cs0, sn1, cs1, aFB);
    }
    {
        const float qC0 = x[sgC * 6 + 0], qC1 = x[sgC * 6 + 1];
        float ss_, cc_;
        sincosf(rb0 ? qC1 : qC0, &ss_, &cc_);
        const float sso = __shfl_xor(ss_, 4), cco = __shfl_xor(cc_, 4);
        const float sn0 = rb0 ? sso : ss_, cs0 = rb0 ? cco : cc_;
        const float sn1 = rb0 ? ss_ : sso, cs1 = rb0 ? cc_ : cco;
        build_aF(w0p, b0, kg, rho, rb0, rb1, sn0, cs0, sn1, cs1, aFC);
    }
    {
        const float qD0 = x[sgD * 6 + 0], qD1 = x[sgD * 6 + 1];
        float ss_, cc_;
        sincosf(rb0 ? qD1 : qD0, &ss_, &cc_);
        const float sso = __shfl_xor(ss_, 4), cco = __shfl_xor(cc_, 4);
        const float sn0 = rb0 ? sso : ss_, cs0 = rb0 ? cco : cc_;
        const float sn1 = rb0 ? ss_ : sso, cs1 = rb0 ? cc_ : cco;
        build_aF(w0p, b0, kg, rho, rb0, rb1, sn0, cs0, sn1, cs1, aFD);
    }

    float uA0[4] = {0,0,0,0}, uA1[4] = {0,0,0,0}, uA2[4] = {0,0,0,0}, uA3[4] = {0,0,0,0};
    float uB0[4] = {0,0,0,0}, uB1[4] = {0,0,0,0}, uB2[4] = {0,0,0,0}, uB3[4] = {0,0,0,0};
    float uC0[4] = {0,0,0,0}, uC1[4] = {0,0,0,0}, uC2[4] = {0,0,0,0}, uC3[4] = {0,0,0,0};
    float uD0[4] = {0,0,0,0}, uD1[4] = {0,0,0,0}, uD2[4] = {0,0,0,0}, uD3[4] = {0,0,0,0};
    const int col = lane & 15;
    const int q   = lane >> 4;
    const bool qb0 = (q & 1) != 0;
    const bool qb1 = (q & 2) != 0;
    const bool qlt2 = (q < 2);

    const short8* __restrict__ W8 = reinterpret_cast<const short8*>(wB);

    #pragma unroll 1
    for (int nt = 0; nt < 16; ++nt) {
        const int base = nt * 1024 + lane;
        const int ncol = nt * 16 + col;
        const float4 hw  = hwp[ncol];
        const float  b1v = b1[ncol];

        f32x4 cA = {0.f,0.f,0.f,0.f};
        f32x4 cB = {0.f,0.f,0.f,0.f};
        f32x4 cC = {0.f,0.f,0.f,0.f};
        f32x4 cD = {0.f,0.f,0.f,0.f};
        #pragma unroll
        for (int ks = 0; ks < 8; ++ks) {
            const short8 bh = W8[base + ks * 64];
            const short8 bl = W8[base + 512 + ks * 64];
            cA = __builtin_amdgcn_mfma_f32_16x16x32_bf16(aFA[ks], bh, cA, 0, 0, 0);
            cA = __builtin_amdgcn_mfma_f32_16x16x32_bf16(aFA[ks], bl, cA, 0, 0, 0);
            cB = __builtin_amdgcn_mfma_f32_16x16x32_bf16(aFB[ks], bh, cB, 0, 0, 0);
            cB = __builtin_amdgcn_mfma_f32_16x16x32_bf16(aFB[ks], bl, cB, 0, 0, 0);
            cC = __builtin_amdgcn_mfma_f32_16x16x32_bf16(aFC[ks], bh, cC, 0, 0, 0);
            cC = __builtin_amdgcn_mfma_f32_16x16x32_bf16(aFC[ks], bl, cC, 0, 0, 0);
            cD = __builtin_amdgcn_mfma_f32_16x16x32_bf16(aFD[ks], bh, cD, 0, 0, 0);
            cD = __builtin_amdgcn_mfma_f32_16x16x32_bf16(aFD[ks], bl, cD, 0, 0, 0);
        }

        epi_acc(cA, b1v, hw, qb0, qb1, qlt2, uA0, uA1, uA2, uA3);
        epi_acc(cB, b1v, hw, qb0, qb1, qlt2, uB0, uB1, uB2, uB3);
        epi_acc(cC, b1v, hw, qb0, qb1, qlt2, uC0, uC1, uC2, uC3);
        epi_acc(cD, b1v, hw, qb0, qb1, qlt2, uD0, uD1, uD2, uD3);
    }

    // ---------------- column reduction across the 16 cols ----------------
    #pragma unroll
    for (int r = 0; r < 4; ++r) {
        #pragma unroll
        for (int m = 1; m < 16; m <<= 1) {
            uA0[r] += __shfl_xor(uA0[r], m);
            uA1[r] += __shfl_xor(uA1[r], m);
            uA2[r] += __shfl_xor(uA2[r], m);
            uA3[r] += __shfl_xor(uA3[r], m);
            uB0[r] += __shfl_xor(uB0[r], m);
            uB1[r] += __shfl_xor(uB1[r], m);
            uB2[r] += __shfl_xor(uB2[r], m);
            uB3[r] += __shfl_xor(uB3[r], m);
            uC0[r] += __shfl_xor(uC0[r], m);
            uC1[r] += __shfl_xor(uC1[r], m);
            uC2[r] += __shfl_xor(uC2[r], m);
            uC3[r] += __shfl_xor(uC3[r], m);
            uD0[r] += __shfl_xor(uD0[r], m);
            uD1[r] += __shfl_xor(uD1[r], m);
            uD2[r] += __shfl_xor(uD2[r], m);
            uD3[r] += __shfl_xor(uD3[r], m);
        }
    }
    // gather tangent sums onto q0: pa from q2 (xor32), pb from q3 (xor48)
    float paA0[4], paA1[4], paA2[4], paA3[4], pbA0[4], pbA1[4], pbA2[4], pbA3[4];
    float paB0[4], paB1[4], paB2[4], paB3[4], pbB0[4], pbB1[4], pbB2[4], pbB3[4];
    float paC0[4], paC1[4], paC2[4], paC3[4], pbC0[4], pbC1[4], pbC2[4], pbC3[4];
    float paD0[4], paD1[4], paD2[4], paD3[4], pbD0[4], pbD1[4], pbD2[4], pbD3[4];
    #pragma unroll
    for (int r = 0; r < 4; ++r) {
        paA0[r] = __shfl_xor(uA0[r], 32);
        paA1[r] = __shfl_xor(uA1[r], 32);
        paA2[r] = __shfl_xor(uA2[r], 32);
        paA3[r] = __shfl_xor(uA3[r], 32);
        pbA0[r] = __shfl_xor(uA0[r], 48);
        pbA1[r] = __shfl_xor(uA1[r], 48);
        pbA2[r] = __shfl_xor(uA2[r], 48);
        pbA3[r] = __shfl_xor(uA3[r], 48);
        paB0[r] = __shfl_xor(uB0[r], 32);
        paB1[r] = __shfl_xor(uB1[r], 32);
        paB2[r] = __shfl_xor(uB2[r], 32);
        paB3[r] = __shfl_xor(uB3[r], 32);
        pbB0[r] = __shfl_xor(uB0[r], 48);
        pbB1[r] = __shfl_xor(uB1[r], 48);
        pbB2[r] = __shfl_xor(uB2[r], 48);
        pbB3[r] = __shfl_xor(uB3[r], 48);
        paC0[r] = __shfl_xor(uC0[r], 32);
        paC1[r] = __shfl_xor(uC1[r], 32);
        paC2[r] = __shfl_xor(uC2[r], 32);
        paC3[r] = __shfl_xor(uC3[r], 32);
        pbC0[r] = __shfl_xor(uC0[r], 48);
        pbC1[r] = __shfl_xor(uC1[r], 48);
        pbC2[r] = __shfl_xor(uC2[r], 48);
        pbC3[r] = __shfl_xor(uC3[r], 48);
        paD0[r] = __shfl_xor(uD0[r], 32);
        paD1[r] = __shfl_xor(uD1[r], 32);
        paD2[r] = __shfl_xor(uD2[r], 32);
        paD3[r] = __shfl_xor(uD3[r], 32);
        pbD0[r] = __shfl_xor(uD0[r], 48);
        pbD1[r] = __shfl_xor(uD1[r], 48);
        pbD2[r] = __shfl_xor(uD2[r], 48);
        pbD3[r] = __shfl_xor(uD3[r], 48);
    }

    if (lane == 0) {
        const float bd0 = bd[0], bd1 = bd[1], bo0 = bo[0];
        const int base = blockIdx.x * SB + wave * 16;
        #pragma unroll
        for (int r = 0; r < 4; ++r) {
            if (base + r < n)
                solve_write(x, out, base + r,
                            uA0[r], uA1[r], uA2[r],
                            paA0[r], paA1[r], paA2[r], paA3[r],
                            pbA0[r], pbA1[r], pbA2[r], pbA3[r], bd0, bd1, bo0);
            if (base + 4 + r < n)
                solve_write(x, out, base + 4 + r,
                            uB0[r], uB1[r], uB2[r],
                            paB0[r], paB1[r], paB2[r], paB3[r],
                            pbB0[r], pbB1[r], pbB2[r], pbB3[r], bd0, bd1, bo0);
            if (base + 8 + r < n)
                solve_write(x, out, base + 8 + r,
                            uC0[r], uC1[r], uC2[r],
                            paC0[r], paC1[r], paC2[r], paC3[r],
                            pbC0[r], pbC1[r], pbC2[r], pbC3[r], bd0, bd1, bo0);
            if (base + 12 + r < n)
                solve_write(x, out, base + 12 + r,
                            uD0[r], uD1[r], uD2[r],
                            paD0[r], paD1[r], paD2[r], paD3[r],
                            pbD0[r], pbD1[r], pbD2[r], pbD3[r], bd0, bd1, bo0);
        }
    }
}

extern "C" void kernel_launch(void* const* d_in, const int* in_sizes, int n_in,
                              void* d_out, int out_size, void* d_ws, size_t ws_size,
                              hipStream_t stream) {
    // dict order: t, x, W0, b0, W1, b1, Wd, bd, Wo, bo, Wv, bv
    const float* x  = (const float*)d_in[1];
    const float* W0 = (const float*)d_in[2];
    const float* b0 = (const float*)d_in[3];
    const float* W1 = (const float*)d_in[4];
    const float* b1 = (const float*)d_in[5];
    const float* Wd = (const float*)d_in[6];
    const float* bd = (const float*)d_in[7];
    const float* Wo = (const float*)d_in[8];
    const float* bo = (const float*)d_in[9];
    const float* Wv = (const float*)d_in[10];
    float* out = (float*)d_out;

    unsigned short* wB = (unsigned short*)d_ws;                         // 256 KB
    float4* w0p = (float4*)((char*)d_ws + 262144);                      // 4 KB
    float4* hwp = (float4*)((char*)d_ws + 262144 + 4096);               // 4 KB

    const int n = in_sizes[1] / 6;

    prep<<<32, 256, 0, stream>>>(W1, W0, Wd, Wo, Wv, wB, w0p, hwp);

    const int grid = (n + SB - 1) / SB;
    lode_mfma<<<grid, NTHREADS, 0, stream>>>(x, w0p, b0, wB, b1, hwp, bd, bo, out, n);
}

// Round 19
// 336.719 us; speedup vs baseline: 1.6395x; 1.6395x over previous
//
#include <hip/hip_runtime.h>
#include <math.h>

#define SB 32          // samples per block (8 per wave, 4 waves)
#define NTHREADS 256

typedef short short8 __attribute__((ext_vector_type(8)));
typedef float f32x4  __attribute__((ext_vector_type(4)));

__device__ __forceinline__ unsigned short f2bf(float f) {
    unsigned int u = __builtin_bit_cast(unsigned int, f);
    unsigned int r = (u + 0x7FFFu + ((u >> 16) & 1u)) >> 16;   // RNE
    return (unsigned short)r;
}
__device__ __forceinline__ float bf2f(unsigned short h) {
    unsigned int u = ((unsigned int)h) << 16;
    return __builtin_bit_cast(float, u);
}
__device__ __forceinline__ unsigned pack2(unsigned short lo, unsigned short hi) {
    return (unsigned)lo | ((unsigned)hi << 16);
}
__device__ __forceinline__ float softplus_f(float z) {
    return z > 15.f ? z : log1pf(expf(z));
}
__device__ __forceinline__ float fast_tanh(float z) {
    const float e = __builtin_amdgcn_exp2f(z * 2.8853900817779268f);
    return fmaf(-2.f, __builtin_amdgcn_rcpf(e + 1.f), 1.f);
}
__device__ __forceinline__ unsigned selv(bool c, unsigned a, unsigned b) {
    return c ? a : b;
}
__device__ __forceinline__ unsigned sx(unsigned v, int m) {
    return (unsigned)__shfl_xor((int)v, m);
}

// ---------------- prep: pack W1 (split hi/lo) + W0 + head weights ----------------
// wB (short8 slots): nt*1024 + [hi: ks*64+l | lo: 512+ks*64+l]
// slot element i: B[k][n], k = ks*32 + (l>>4)*8 + i, n = nt*16 + (l&15)
__global__ void prep(const float* __restrict__ W1, const float* __restrict__ W0,
                     const float* __restrict__ Wd, const float* __restrict__ Wo,
                     const float* __restrict__ Wv,
                     unsigned short* __restrict__ wB,
                     float4* __restrict__ w0p, float4* __restrict__ hwp)
{
    int idx = blockIdx.x * blockDim.x + threadIdx.x;
    if (idx < 256) {
        w0p[idx] = make_float4(W0[idx], W0[256 + idx], W0[512 + idx], W0[768 + idx]);
        hwp[idx] = make_float4(Wd[2 * idx], Wd[2 * idx + 1], Wo[idx], Wv[idx]);
    }
    if (idx < 8192) {
        const int l  = idx & 63;
        const int ks = (idx >> 6) & 7;
        const int nt = idx >> 9;
        const int k0 = ks * 32 + (l >> 4) * 8;
        const int n  = nt * 16 + (l & 15);
        const int hbase = (nt * 1024 + ks * 64 + l) * 8;
        const int lbase = (nt * 1024 + 512 + ks * 64 + l) * 8;
        #pragma unroll
        for (int i = 0; i < 8; ++i) {
            const float f = W1[(k0 + i) * 256 + n];
            const unsigned short hi = f2bf(f);
            const unsigned short lo = f2bf(f - bf2f(hi));
            wB[hbase + i] = hi;
            wB[lbase + i] = lo;
        }
    }
}

// Build one 16-row A fragment set (rows = rho*4+s: h_hi,h_lo,ta,tb x 4 samples).
// Identical arithmetic + exchange (xor 4/8/12) to the r9/r11-passing kernels.
__device__ __forceinline__ void build_aF(
    const float4* __restrict__ w0p, const float* __restrict__ b0,
    int kg, int rho, bool rb0, bool rb1,
    float sn0, float cs0, float sn1, float cs1, short8* aF)
{
    #pragma unroll
    for (int ks = 0; ks < 8; ++ks) {
        const int j0 = ks * 32 + kg * 8 + 2 * rho;
        const float4 wa = w0p[j0];
        const float4 wb = w0p[j0 + 1];
        const float2 bb = *reinterpret_cast<const float2*>(&b0[j0]);
        float z0 = bb.x;
        z0 = fmaf(cs0, wa.x, z0); z0 = fmaf(cs1, wa.y, z0);
        z0 = fmaf(sn0, wa.z, z0); z0 = fmaf(sn1, wa.w, z0);
        float z1 = bb.y;
        z1 = fmaf(cs0, wb.x, z1); z1 = fmaf(cs1, wb.y, z1);
        z1 = fmaf(sn0, wb.z, z1); z1 = fmaf(sn1, wb.w, z1);
        const float h0 = fast_tanh(z0);
        const float h1 = fast_tanh(z1);
        const unsigned short h0h = f2bf(h0);
        const unsigned short h1h = f2bf(h1);
        const unsigned short h0l = f2bf(h0 - bf2f(h0h));
        const unsigned short h1l = f2bf(h1 - bf2f(h1h));
        const float dt0 = fmaf(-h0, h0, 1.f);
        const float dt1 = fmaf(-h1, h1, 1.f);
        const float ta0 = dt0 * fmaf(-sn0, wa.x, cs0 * wa.z);
        const float ta1 = dt1 * fmaf(-sn0, wb.x, cs0 * wb.z);
        const float tb0 = dt0 * fmaf(-sn1, wa.y, cs1 * wa.w);
        const float tb1 = dt1 * fmaf(-sn1, wb.y, cs1 * wb.w);
        const unsigned v0 = pack2(h0h, h1h);
        const unsigned v1 = pack2(h0l, h1l);
        const unsigned v2 = pack2(f2bf(ta0), f2bf(ta1));
        const unsigned v3 = pack2(f2bf(tb0), f2bf(tb1));
        const unsigned s0 = selv(rb1, selv(rb0, v3, v2), selv(rb0, v1, v0));
        const unsigned s1 = selv(rb1, selv(rb0, v2, v3), selv(rb0, v0, v1));
        const unsigned s2 = selv(rb1, selv(rb0, v1, v0), selv(rb0, v3, v2));
        const unsigned s3 = selv(rb1, selv(rb0, v0, v1), selv(rb0, v2, v3));
        const unsigned r4  = sx(s1, 4);
        const unsigned r8  = sx(s2, 8);
        const unsigned r12 = sx(s3, 12);
        const unsigned w0 = selv(rb1, selv(rb0, r12, r8), selv(rb0, r4, s0));
        const unsigned w1 = selv(rb1, selv(rb0, r8, r12), selv(rb0, s0, r4));
        const unsigned w2 = selv(rb1, selv(rb0, r4, s0), selv(rb0, r12, r8));
        const unsigned w3 = selv(rb1, selv(rb0, s0, r4), selv(rb0, r8, r12));
        aF[ks] = __builtin_bit_cast(short8, make_uint4(w0, w1, w2, w3));
    }
}

// r9/r11's quadrant-dedup'd epilogue accumulation (1 tanh/lane/call).
__device__ __forceinline__ void epi_acc(
    const f32x4& c1, const f32x4& c2, float b1v, const float4& hw,
    bool qb0, bool qb1, bool qlt2,
    float* u0, float* u1, float* u2, float* u3)
{
    float zs[4], zf[4], zA[4];
    #pragma unroll
    for (int r = 0; r < 4; ++r) zs[r] = c1[r] + c2[r];
    #pragma unroll
    for (int r = 0; r < 4; ++r) zf[r] = zs[r] + __shfl_xor(zs[r], 16) + b1v;
    #pragma unroll
    for (int r = 0; r < 4; ++r) {
        const float zr = __shfl_xor(zf[r], 32);
        zA[r] = qlt2 ? zf[r] : zr;
    }
    const float zpick = qb1 ? (qb0 ? zA[3] : zA[2]) : (qb0 ? zA[1] : zA[0]);
    const float hq = fast_tanh(zpick);
    const float g1 = __shfl_xor(hq, 16);
    const float g2 = __shfl_xor(hq, 32);
    const float g3 = __shfl_xor(hq, 48);
    float hr[4];
    hr[0] = qb1 ? (qb0 ? g3 : g2) : (qb0 ? g1 : hq);
    hr[1] = qb1 ? (qb0 ? g2 : g3) : (qb0 ? hq : g1);
    hr[2] = qb1 ? (qb0 ? g1 : hq) : (qb0 ? g3 : g2);
    hr[3] = qb1 ? (qb0 ? hq : g1) : (qb0 ? g2 : g3);
    #pragma unroll
    for (int r = 0; r < 4; ++r) {
        const float dt  = fmaf(-hr[r], hr[r], 1.f);
        const float val = qlt2 ? hr[r] : dt * zs[r];
        u0[r] = fmaf(val, hw.x, u0[r]);
        u1[r] = fmaf(val, hw.y, u1[r]);
        u2[r] = fmaf(val, hw.z, u2[r]);
        u3[r] = fmaf(val, hw.w, u3[r]);
    }
}

// scalar per-sample dynamics solve + output write (r11 body, unchanged)
__device__ __forceinline__ void solve_write(
    const float* __restrict__ x, float* __restrict__ out, int sg,
    float phd0, float phd1, float phoo,
    float pad0, float pad1, float pao, float pav,
    float pbd0, float pbd1, float pbo, float pbv,
    float bd0, float bd1, float bo0)
{
    const float u    = x[sg * 6 + 2];
    const float vv   = x[sg * 6 + 3];
    const float tau0 = x[sg * 6 + 4];
    const float tau1 = x[sg * 6 + 5];

    const float zd0 = phd0 + bd0;
    const float zd1 = phd1 + bd1;
    const float zo  = phoo + bo0;

    const float ld0 = softplus_f(zd0) + 1e-4f;
    const float ld1 = softplus_f(zd1) + 1e-4f;
    const float lo  = zo;

    const float sg0 = 1.f / (1.f + expf(-zd0));
    const float sg1 = 1.f / (1.f + expf(-zd1));

    const float ld0a = sg0 * pad0, ld0b = sg0 * pbd0;
    const float ld1a = sg1 * pad1, ld1b = sg1 * pbd1;
    const float loa  = pao,        lob  = pbo;
    const float ga   = pav,        gb   = pbv;

    const float H00 = fmaf(ld0, ld0, 1e-4f);
    const float H01 = ld0 * lo;
    const float H11 = fmaf(lo, lo, fmaf(ld1, ld1, 1e-4f));

    const float dH00a = 2.f * ld0 * ld0a, dH00b = 2.f * ld0 * ld0b;
    const float dH01a = fmaf(ld0a, lo, ld0 * loa);
    const float dH01b = fmaf(ld0b, lo, ld0 * lob);
    const float dH11a = 2.f * fmaf(lo, loa, ld1 * ld1a);
    const float dH11b = 2.f * fmaf(lo, lob, ld1 * ld1b);

    const float wa0 = fmaf(dH00a, u, dH01a * vv);
    const float wa1 = fmaf(dH01a, u, dH11a * vv);
    const float wb0 = fmaf(dH00b, u, dH01b * vv);
    const float wb1 = fmaf(dH01b, u, dH11b * vv);

    const float QFa = dH00a*u*u + 2.f*dH01a*u*vv + dH11a*vv*vv;
    const float QFb = dH00b*u*u + 2.f*dH01b*u*vv + dH11b*vv*vv;

    const float C0 = fmaf(wa0, u, wb0 * vv) - 0.5f * QFa;
    const float C1 = fmaf(wa1, u, wb1 * vv) - 0.5f * QFb;

    const float r0 = tau0 - C0 - ga;
    const float r1 = tau1 - C1 - gb;

    const float det = fmaf(H00, H11, -H01 * H01);
    const float inv = 1.f / det;
    const float qdd0 = (H11 * r0 - H01 * r1) * inv;
    const float qdd1 = (H00 * r1 - H01 * r0) * inv;

    float2* o = reinterpret_cast<float2*>(&out[sg * 6]);
    o[0] = make_float2(u, vv);
    o[1] = make_float2(qdd0, qdd1);
    o[2] = make_float2(0.f, 0.f);
}

// r17 barrier-free skeleton; ONLY change: nt loop unroll 1 -> 2 so the
// compiler can overlap iteration nt+1's B-loads with iteration nt's
// MFMA+epilogue (no barriers to stop it).
__global__ __launch_bounds__(NTHREADS, 1)
void lode_mfma(const float* __restrict__ x,
               const float4* __restrict__ w0p, const float* __restrict__ b0,
               const unsigned short* __restrict__ wB,
               const float* __restrict__ b1,
               const float4* __restrict__ hwp,
               const float* __restrict__ bd, const float* __restrict__ bo,
               float* __restrict__ out, int n)
{
    const int tid  = threadIdx.x;
    const int wave = tid >> 6;
    const int lane = tid & 63;
    const int r15  = lane & 15;
    const int s    = r15 & 3;
    const int rho  = r15 >> 2;
    const bool rb0 = (rho & 1) != 0;
    const bool rb1 = (rho & 2) != 0;
    const int kg   = lane >> 4;

    // ---------------- phase 1: two A-fragment sets (samples wave*8+s / +4+s) ----
    int sgA = blockIdx.x * SB + wave * 8 + s;
    int sgB = sgA + 4;
    if (sgA >= n) sgA = n - 1;
    if (sgB >= n) sgB = n - 1;
    const float qA0 = x[sgA * 6 + 0];
    const float qA1 = x[sgA * 6 + 1];
    const float qB0 = x[sgB * 6 + 0];
    const float qB1 = x[sgB * 6 + 1];
    float ssA, ccA, ssB, ccB;
    sincosf(rb0 ? qA1 : qA0, &ssA, &ccA);
    sincosf(rb0 ? qB1 : qB0, &ssB, &ccB);
    const float ssAo = __shfl_xor(ssA, 4), ccAo = __shfl_xor(ccA, 4);
    const float ssBo = __shfl_xor(ssB, 4), ccBo = __shfl_xor(ccB, 4);
    const float snA0 = rb0 ? ssAo : ssA, csA0 = rb0 ? ccAo : ccA;
    const float snA1 = rb0 ? ssA : ssAo, csA1 = rb0 ? ccA : ccAo;
    const float snB0 = rb0 ? ssBo : ssB, csB0 = rb0 ? ccBo : ccB;
    const float snB1 = rb0 ? ssB : ssBo, csB1 = rb0 ? ccB : ccBo;

    short8 aFA[8], aFB[8];
    build_aF(w0p, b0, kg, rho, rb0, rb1, snA0, csA0, snA1, csA1, aFA);
    build_aF(w0p, b0, kg, rho, rb0, rb1, snB0, csB0, snB1, csB1, aFB);

    float uA0[4] = {0,0,0,0}, uA1[4] = {0,0,0,0}, uA2[4] = {0,0,0,0}, uA3[4] = {0,0,0,0};
    float uB0[4] = {0,0,0,0}, uB1[4] = {0,0,0,0}, uB2[4] = {0,0,0,0}, uB3[4] = {0,0,0,0};
    const int col = lane & 15;
    const int q   = lane >> 4;
    const bool qb0 = (q & 1) != 0;
    const bool qb1 = (q & 2) != 0;
    const bool qlt2 = (q < 2);

    const short8* __restrict__ W8 = reinterpret_cast<const short8*>(wB);

    #pragma unroll 2
    for (int nt = 0; nt < 16; ++nt) {
        const int base = nt * 1024 + lane;
        const int ncol = nt * 16 + col;
        const float4 hw  = hwp[ncol];
        const float  b1v = b1[ncol];

        // stream B tile L2 -> registers (r5-proven path; no LDS, no barrier)
        short8 bh[8], bl[8];
        #pragma unroll
        for (int ks = 0; ks < 8; ++ks) {
            bh[ks] = W8[base + ks * 64];
            bl[ks] = W8[base + 512 + ks * 64];
        }

        f32x4 c1A = {0.f,0.f,0.f,0.f}, c2A = {0.f,0.f,0.f,0.f};
        f32x4 c1B = {0.f,0.f,0.f,0.f}, c2B = {0.f,0.f,0.f,0.f};
        #pragma unroll
        for (int ks = 0; ks < 8; ++ks) {
            c1A = __builtin_amdgcn_mfma_f32_16x16x32_bf16(aFA[ks], bh[ks], c1A, 0, 0, 0);
            c2A = __builtin_amdgcn_mfma_f32_16x16x32_bf16(aFA[ks], bl[ks], c2A, 0, 0, 0);
            c1B = __builtin_amdgcn_mfma_f32_16x16x32_bf16(aFB[ks], bh[ks], c1B, 0, 0, 0);
            c2B = __builtin_amdgcn_mfma_f32_16x16x32_bf16(aFB[ks], bl[ks], c2B, 0, 0, 0);
        }

        epi_acc(c1A, c2A, b1v, hw, qb0, qb1, qlt2, uA0, uA1, uA2, uA3);
        epi_acc(c1B, c2B, b1v, hw, qb0, qb1, qlt2, uB0, uB1, uB2, uB3);
    }

    // ---------------- column reduction across the 16 cols ----------------
    #pragma unroll
    for (int r = 0; r < 4; ++r) {
        #pragma unroll
        for (int m = 1; m < 16; m <<= 1) {
            uA0[r] += __shfl_xor(uA0[r], m);
            uA1[r] += __shfl_xor(uA1[r], m);
            uA2[r] += __shfl_xor(uA2[r], m);
            uA3[r] += __shfl_xor(uA3[r], m);
            uB0[r] += __shfl_xor(uB0[r], m);
            uB1[r] += __shfl_xor(uB1[r], m);
            uB2[r] += __shfl_xor(uB2[r], m);
            uB3[r] += __shfl_xor(uB3[r], m);
        }
    }
    // gather tangent sums onto q0: pa from q2 (xor32), pb from q3 (xor48)
    float paA0[4], paA1[4], paA2[4], paA3[4], pbA0[4], pbA1[4], pbA2[4], pbA3[4];
    float paB0[4], paB1[4], paB2[4], paB3[4], pbB0[4], pbB1[4], pbB2[4], pbB3[4];
    #pragma unroll
    for (int r = 0; r < 4; ++r) {
        paA0[r] = __shfl_xor(uA0[r], 32);
        paA1[r] = __shfl_xor(uA1[r], 32);
        paA2[r] = __shfl_xor(uA2[r], 32);
        paA3[r] = __shfl_xor(uA3[r], 32);
        pbA0[r] = __shfl_xor(uA0[r], 48);
        pbA1[r] = __shfl_xor(uA1[r], 48);
        pbA2[r] = __shfl_xor(uA2[r], 48);
        pbA3[r] = __shfl_xor(uA3[r], 48);
        paB0[r] = __shfl_xor(uB0[r], 32);
        paB1[r] = __shfl_xor(uB1[r], 32);
        paB2[r] = __shfl_xor(uB2[r], 32);
        paB3[r] = __shfl_xor(uB3[r], 32);
        pbB0[r] = __shfl_xor(uB0[r], 48);
        pbB1[r] = __shfl_xor(uB1[r], 48);
        pbB2[r] = __shfl_xor(uB2[r], 48);
        pbB3[r] = __shfl_xor(uB3[r], 48);
    }

    if (lane == 0) {
        const float bd0 = bd[0], bd1 = bd[1], bo0 = bo[0];
        const int base = blockIdx.x * SB + wave * 8;
        #pragma unroll
        for (int r = 0; r < 4; ++r) {
            if (base + r < n)
                solve_write(x, out, base + r,
                            uA0[r], uA1[r], uA2[r],
                            paA0[r], paA1[r], paA2[r], paA3[r],
                            pbA0[r], pbA1[r], pbA2[r], pbA3[r], bd0, bd1, bo0);
            if (base + 4 + r < n)
                solve_write(x, out, base + 4 + r,
                            uB0[r], uB1[r], uB2[r],
                            paB0[r], paB1[r], paB2[r], paB3[r],
                            pbB0[r], pbB1[r], pbB2[r], pbB3[r], bd0, bd1, bo0);
        }
    }
}

extern "C" void kernel_launch(void* const* d_in, const int* in_sizes, int n_in,
                              void* d_out, int out_size, void* d_ws, size_t ws_size,
                              hipStream_t stream) {
    // dict order: t, x, W0, b0, W1, b1, Wd, bd, Wo, bo, Wv, bv
    const float* x  = (const float*)d_in[1];
    const float* W0 = (const float*)d_in[2];
    const float* b0 = (const float*)d_in[3];
    const float* W1 = (const float*)d_in[4];
    const float* b1 = (const float*)d_in[5];
    const float* Wd = (const float*)d_in[6];
    const float* bd = (const float*)d_in[7];
    const float* Wo = (const float*)d_in[8];
    const float* bo = (const float*)d_in[9];
    const float* Wv = (const float*)d_in[10];
    float* out = (float*)d_out;

    unsigned short* wB = (unsigned short*)d_ws;                         // 256 KB
    float4* w0p = (float4*)((char*)d_ws + 262144);                      // 4 KB
    float4* hwp = (float4*)((char*)d_ws + 262144 + 4096);               // 4 KB

    const int n = in_sizes[1] / 6;

    prep<<<32, 256, 0, stream>>>(W1, W0, Wd, Wo, Wv, wB, w0p, hwp);

    const int grid = (n + SB - 1) / SB;
    lode_mfma<<<grid, NTHREADS, 0, stream>>>(x, w0p, b0, wB, b1, hwp, bd, bo, out, n);
}